// Round 4
// baseline (269.730 us; speedup 1.0000x reference)
//
#include <hip/hip_runtime.h>

// Problem constants (match reference setup_inputs)
constexpr int BB = 4;
constexpr int NN = 40960;
constexpr int KK = 16;
constexpr int DD = 8;
constexpr float BN_EPS = 1e-6f;

constexpr int TOTAL4 = BB * NN * (KK / 4);   // 655360 work items (4 k each)

// Stats: 512 blocks x 1024 threads -> 16 waves/CU resident (vs 8 before),
// better gather-latency hiding. Partials stay at 512x16 floats so the
// verified finalize kernel + ws layout are unchanged.
constexpr int STATS_BLOCKS  = 512;
constexpr int STATS_THREADS = 1024;

// native vector type for nontemporal stores (HIP float4 is a class type,
// rejected by __builtin_nontemporal_store)
typedef float f32x4 __attribute__((ext_vector_type(4)));

// ws layout (floats):
//   [0 .. STATS_BLOCKS*16)            per-block partials (8 sums, 8 sumsqs)
//   [STATS_BLOCKS*16 .. +80)          W' (BN-folded conv weight, 8x10)
//   [STATS_BLOCKS*16+80 .. +88)       b' (BN-folded bias, 8)

// h = W . [c, nb, c-nb, dist] + b  ==  (b + A.c) + B.nb + w9*dist
//   A[d][j] = W[d][j] + W[d][6+j],  B[d][j] = W[d][3+j] - W[d][6+j]
// (fold is linear, so it applies equally to the BN-scaled wp/bp)

__global__ __launch_bounds__(STATS_THREADS, 4) void locse_stats_kernel(
    const float* __restrict__ coords, const int* __restrict__ idx,
    const float* __restrict__ dist, const float* __restrict__ W,
    const float* __restrict__ bias, float* __restrict__ partials)
{
    __shared__ float sA[24];   // [d][j]
    __shared__ float sB[24];
    __shared__ float sw9[8];
    __shared__ float sbb[8];
    if (threadIdx.x < 24) {
        const int d = threadIdx.x / 3, j = threadIdx.x % 3;
        sA[threadIdx.x] = W[d * 10 + j] + W[d * 10 + 6 + j];
        sB[threadIdx.x] = W[d * 10 + 3 + j] - W[d * 10 + 6 + j];
    }
    if (threadIdx.x < 8) {
        sw9[threadIdx.x] = W[threadIdx.x * 10 + 9];
        sbb[threadIdx.x] = bias[threadIdx.x];
    }
    __syncthreads();

    float sum[8] = {0.f, 0.f, 0.f, 0.f, 0.f, 0.f, 0.f, 0.f};
    float sq[8]  = {0.f, 0.f, 0.f, 0.f, 0.f, 0.f, 0.f, 0.f};

    for (int t = blockIdx.x * blockDim.x + threadIdx.x; t < TOTAL4;
         t += gridDim.x * blockDim.x) {
        const int k4 = t & 3;
        const int bn = t >> 2;               // b*NN + n
        const int b  = bn / NN;
        const float* cc = coords + (size_t)bn * 3;
        const float cx = cc[0], cy = cc[1], cz = cc[2];

        float cA[8];
        #pragma unroll
        for (int d = 0; d < 8; ++d)
            cA[d] = fmaf(sA[d * 3 + 2], cz,
                    fmaf(sA[d * 3 + 1], cy,
                    fmaf(sA[d * 3 + 0], cx, sbb[d])));

        const int base = (bn << 4) + (k4 << 2);   // 16B aligned
        const int4   j4 = *reinterpret_cast<const int4*>(idx + base);
        const float4 d4 = *reinterpret_cast<const float4*>(dist + base);
        const int   js[4] = {j4.x, j4.y, j4.z, j4.w};
        const float ds[4] = {d4.x, d4.y, d4.z, d4.w};

        #pragma unroll
        for (int kk = 0; kk < 4; ++kk) {
            const float* nc = coords + ((size_t)b * NN + js[kk]) * 3;
            const float nx = nc[0], ny = nc[1], nz = nc[2];
            #pragma unroll
            for (int d = 0; d < 8; ++d) {
                float h = fmaf(sw9[d], ds[kk],
                          fmaf(sB[d * 3 + 2], nz,
                          fmaf(sB[d * 3 + 1], ny,
                          fmaf(sB[d * 3 + 0], nx, cA[d]))));
                sum[d] += h;
                sq[d]  += h * h;
            }
        }
    }

    // wave (64-lane) shuffle reduction for all 16 quantities
    #pragma unroll
    for (int v = 0; v < 8; ++v) {
        float s = sum[v], q = sq[v];
        #pragma unroll
        for (int off = 32; off > 0; off >>= 1) {
            s += __shfl_down(s, off, 64);
            q += __shfl_down(q, off, 64);
        }
        sum[v] = s; sq[v] = q;
    }

    __shared__ float wred[STATS_THREADS / 64][16];
    const int lane = threadIdx.x & 63;
    const int wid  = threadIdx.x >> 6;
    if (lane == 0) {
        #pragma unroll
        for (int v = 0; v < 8; ++v) {
            wred[wid][v]     = sum[v];
            wred[wid][8 + v] = sq[v];
        }
    }
    __syncthreads();
    if (threadIdx.x < 16) {
        float s = 0.f;
        #pragma unroll
        for (int w = 0; w < STATS_THREADS / 64; ++w) s += wred[w][threadIdx.x];
        partials[blockIdx.x * 16 + threadIdx.x] = s;
    }
}

__global__ __launch_bounds__(256) void locse_finalize_kernel(
    const float* __restrict__ partials, const float* __restrict__ W,
    const float* __restrict__ bias, const float* __restrict__ gamma,
    const float* __restrict__ beta, float* __restrict__ wp,
    float* __restrict__ bp)
{
    const int t = threadIdx.x;
    const int c = t & 15;
    float acc = 0.f;
    for (int i = t >> 4; i < STATS_BLOCKS; i += 16) acc += partials[i * 16 + c];

    __shared__ float red[256];
    __shared__ float tot[16];
    __shared__ float scale_s[8];
    red[t] = acc;
    __syncthreads();
    if (t < 16) {
        float s = 0.f;
        #pragma unroll
        for (int i = 0; i < 16; ++i) s += red[i * 16 + t];
        tot[t] = s;
    }
    __syncthreads();
    if (t < 8) {
        const float cnt  = (float)BB * (float)NN * (float)KK;
        const float mean = tot[t] / cnt;
        const float var  = tot[8 + t] / cnt - mean * mean;
        const float sc   = gamma[t] * rsqrtf(var + BN_EPS);
        scale_s[t] = sc;
        bp[t] = fmaf(bias[t] - mean, sc, beta[t]);   // (b - mean)*sc + beta
    }
    __syncthreads();
    if (t < 80) wp[t] = W[t] * scale_s[t / 10];
}

__global__ __launch_bounds__(256) void locse_out_kernel(
    const float* __restrict__ coords, const float* __restrict__ features,
    const int* __restrict__ idx, const float* __restrict__ dist,
    const float* __restrict__ wp, const float* __restrict__ bp,
    float* __restrict__ out)
{
    __shared__ float sA[24];
    __shared__ float sB[24];
    __shared__ float sw9[8];
    __shared__ float sbb[8];
    if (threadIdx.x < 24) {
        const int d = threadIdx.x / 3, j = threadIdx.x % 3;
        sA[threadIdx.x] = wp[d * 10 + j] + wp[d * 10 + 6 + j];
        sB[threadIdx.x] = wp[d * 10 + 3 + j] - wp[d * 10 + 6 + j];
    }
    if (threadIdx.x < 8) {
        sw9[threadIdx.x] = wp[threadIdx.x * 10 + 9];
        sbb[threadIdx.x] = bp[threadIdx.x];
    }
    __syncthreads();

    const int t = blockIdx.x * blockDim.x + threadIdx.x;   // grid == TOTAL4 exactly
    const int k4 = t & 3;
    const int bn = t >> 2;
    const int b  = bn / NN;
    const int n  = bn - b * NN;
    const float* cc = coords + (size_t)bn * 3;
    const float cx = cc[0], cy = cc[1], cz = cc[2];

    float cA[8];
    #pragma unroll
    for (int d = 0; d < 8; ++d)
        cA[d] = fmaf(sA[d * 3 + 2], cz,
                fmaf(sA[d * 3 + 1], cy,
                fmaf(sA[d * 3 + 0], cx, sbb[d])));

    const int base = (bn << 4) + (k4 << 2);
    const int4   j4 = *reinterpret_cast<const int4*>(idx + base);
    const float4 d4 = *reinterpret_cast<const float4*>(dist + base);
    const int   js[4] = {j4.x, j4.y, j4.z, j4.w};
    const float ds[4] = {d4.x, d4.y, d4.z, d4.w};

    float hv[8][4];
    #pragma unroll
    for (int kk = 0; kk < 4; ++kk) {
        const float* nc = coords + ((size_t)b * NN + js[kk]) * 3;
        const float nx = nc[0], ny = nc[1], nz = nc[2];
        #pragma unroll
        for (int d = 0; d < 8; ++d) {
            const float h = fmaf(sw9[d], ds[kk],
                            fmaf(sB[d * 3 + 2], nz,
                            fmaf(sB[d * 3 + 1], ny,
                            fmaf(sB[d * 3 + 0], nx, cA[d]))));
            hv[d][kk] = fmaxf(h, 0.f);
        }
    }

    // out[b, ch, n, k]: base offset for (b, ch=0, n, k4*4)
    const size_t outn = (size_t)b * 16 * NN * KK + (size_t)n * KK + (k4 << 2);
    #pragma unroll
    for (int d = 0; d < 8; ++d) {
        f32x4* p = reinterpret_cast<f32x4*>(out + outn + (size_t)d * NN * KK);
        const f32x4 v = {hv[d][0], hv[d][1], hv[d][2], hv[d][3]};
        __builtin_nontemporal_store(v, p);
    }
    #pragma unroll
    for (int d = 0; d < 8; ++d) {
        const float f = features[((size_t)b * DD + d) * NN + n];
        f32x4* p = reinterpret_cast<f32x4*>(out + outn + (size_t)(8 + d) * NN * KK);
        const f32x4 v = {f, f, f, f};
        __builtin_nontemporal_store(v, p);
    }
}

extern "C" void kernel_launch(void* const* d_in, const int* in_sizes, int n_in,
                              void* d_out, int out_size, void* d_ws, size_t ws_size,
                              hipStream_t stream) {
    const float* coords   = (const float*)d_in[0];
    const float* features = (const float*)d_in[1];
    const int*   idx      = (const int*)d_in[2];
    const float* dist     = (const float*)d_in[3];
    const float* W        = (const float*)d_in[4];
    const float* bias     = (const float*)d_in[5];
    const float* gamma    = (const float*)d_in[6];
    const float* beta     = (const float*)d_in[7];
    float* out = (float*)d_out;

    float* wsf      = (float*)d_ws;
    float* partials = wsf;
    float* wp       = wsf + STATS_BLOCKS * 16;
    float* bp       = wp + 80;

    locse_stats_kernel<<<dim3(STATS_BLOCKS), dim3(STATS_THREADS), 0, stream>>>(
        coords, idx, dist, W, bias, partials);
    locse_finalize_kernel<<<dim3(1), dim3(256), 0, stream>>>(
        partials, W, bias, gamma, beta, wp, bp);

    const int blocks = TOTAL4 / 256;   // 2560, exact
    locse_out_kernel<<<dim3(blocks), dim3(256), 0, stream>>>(
        coords, features, idx, dist, wp, bp, out);
}

// Round 5
// 262.666 us; speedup vs baseline: 1.0269x; 1.0269x over previous
//
#include <hip/hip_runtime.h>

// Problem constants (match reference setup_inputs)
constexpr int BB = 4;
constexpr int NN = 40960;
constexpr int KK = 16;
constexpr int DD = 8;
constexpr float BN_EPS = 1e-6f;

constexpr int TOTAL4 = BB * NN * (KK / 4);   // 655360 work items (4 k each)

// Stats: 512 blocks x 640 threads = 327680 threads, exactly 2 items/thread
// (balanced, no tail), 20 waves/CU resident (vs 8 in the 244us baseline).
// Partials stay at 512x16 floats so the verified finalize kernel + ws
// layout are unchanged.
constexpr int STATS_BLOCKS  = 512;
constexpr int STATS_THREADS = 640;
constexpr int STATS_NTHREADS = STATS_BLOCKS * STATS_THREADS;  // 327680
constexpr int STATS_ITEMS    = TOTAL4 / STATS_NTHREADS;       // 2, exact
static_assert(STATS_ITEMS * STATS_NTHREADS == TOTAL4, "balanced grid");

// ws layout (floats):
//   [0 .. STATS_BLOCKS*16)            per-block partials (8 sums, 8 sumsqs)
//   [STATS_BLOCKS*16 .. +80)          W' (BN-folded conv weight, 8x10)
//   [STATS_BLOCKS*16+80 .. +88)       b' (BN-folded bias, 8)

// h = W . [c, nb, c-nb, dist] + b  ==  (b + A.c) + B.nb + w9*dist
//   A[d][j] = W[d][j] + W[d][6+j],  B[d][j] = W[d][3+j] - W[d][6+j]
// (fold is linear, so it applies equally to the BN-scaled wp/bp)

__global__ __launch_bounds__(STATS_THREADS, 5) void locse_stats_kernel(
    const float* __restrict__ coords, const int* __restrict__ idx,
    const float* __restrict__ dist, const float* __restrict__ W,
    const float* __restrict__ bias, float* __restrict__ partials)
{
    __shared__ float sA[24];   // [d][j]
    __shared__ float sB[24];
    __shared__ float sw9[8];
    __shared__ float sbb[8];
    if (threadIdx.x < 24) {
        const int d = threadIdx.x / 3, j = threadIdx.x % 3;
        sA[threadIdx.x] = W[d * 10 + j] + W[d * 10 + 6 + j];
        sB[threadIdx.x] = W[d * 10 + 3 + j] - W[d * 10 + 6 + j];
    }
    if (threadIdx.x < 8) {
        sw9[threadIdx.x] = W[threadIdx.x * 10 + 9];
        sbb[threadIdx.x] = bias[threadIdx.x];
    }
    __syncthreads();

    float sum[8] = {0.f, 0.f, 0.f, 0.f, 0.f, 0.f, 0.f, 0.f};
    float sq[8]  = {0.f, 0.f, 0.f, 0.f, 0.f, 0.f, 0.f, 0.f};

    const int tau = blockIdx.x * STATS_THREADS + threadIdx.x;
    #pragma unroll
    for (int it = 0; it < STATS_ITEMS; ++it) {
        const int t  = tau + it * STATS_NTHREADS;   // coalesced per wave
        const int k4 = t & 3;
        const int bn = t >> 2;               // b*NN + n
        const int b  = bn / NN;
        const float* cc = coords + (size_t)bn * 3;
        const float cx = cc[0], cy = cc[1], cz = cc[2];

        float cA[8];
        #pragma unroll
        for (int d = 0; d < 8; ++d)
            cA[d] = fmaf(sA[d * 3 + 2], cz,
                    fmaf(sA[d * 3 + 1], cy,
                    fmaf(sA[d * 3 + 0], cx, sbb[d])));

        const int base = (bn << 4) + (k4 << 2);   // 16B aligned
        const int4   j4 = *reinterpret_cast<const int4*>(idx + base);
        const float4 d4 = *reinterpret_cast<const float4*>(dist + base);
        const int   js[4] = {j4.x, j4.y, j4.z, j4.w};
        const float ds[4] = {d4.x, d4.y, d4.z, d4.w};

        #pragma unroll
        for (int kk = 0; kk < 4; ++kk) {
            const float* nc = coords + ((size_t)b * NN + js[kk]) * 3;
            const float nx = nc[0], ny = nc[1], nz = nc[2];
            #pragma unroll
            for (int d = 0; d < 8; ++d) {
                float h = fmaf(sw9[d], ds[kk],
                          fmaf(sB[d * 3 + 2], nz,
                          fmaf(sB[d * 3 + 1], ny,
                          fmaf(sB[d * 3 + 0], nx, cA[d]))));
                sum[d] += h;
                sq[d]  += h * h;
            }
        }
    }

    // wave (64-lane) shuffle reduction for all 16 quantities
    #pragma unroll
    for (int v = 0; v < 8; ++v) {
        float s = sum[v], q = sq[v];
        #pragma unroll
        for (int off = 32; off > 0; off >>= 1) {
            s += __shfl_down(s, off, 64);
            q += __shfl_down(q, off, 64);
        }
        sum[v] = s; sq[v] = q;
    }

    __shared__ float wred[STATS_THREADS / 64][16];
    const int lane = threadIdx.x & 63;
    const int wid  = threadIdx.x >> 6;
    if (lane == 0) {
        #pragma unroll
        for (int v = 0; v < 8; ++v) {
            wred[wid][v]     = sum[v];
            wred[wid][8 + v] = sq[v];
        }
    }
    __syncthreads();
    if (threadIdx.x < 16) {
        float s = 0.f;
        #pragma unroll
        for (int w = 0; w < STATS_THREADS / 64; ++w) s += wred[w][threadIdx.x];
        partials[blockIdx.x * 16 + threadIdx.x] = s;
    }
}

__global__ __launch_bounds__(256) void locse_finalize_kernel(
    const float* __restrict__ partials, const float* __restrict__ W,
    const float* __restrict__ bias, const float* __restrict__ gamma,
    const float* __restrict__ beta, float* __restrict__ wp,
    float* __restrict__ bp)
{
    const int t = threadIdx.x;
    const int c = t & 15;
    float acc = 0.f;
    for (int i = t >> 4; i < STATS_BLOCKS; i += 16) acc += partials[i * 16 + c];

    __shared__ float red[256];
    __shared__ float tot[16];
    __shared__ float scale_s[8];
    red[t] = acc;
    __syncthreads();
    if (t < 16) {
        float s = 0.f;
        #pragma unroll
        for (int i = 0; i < 16; ++i) s += red[i * 16 + t];
        tot[t] = s;
    }
    __syncthreads();
    if (t < 8) {
        const float cnt  = (float)BB * (float)NN * (float)KK;
        const float mean = tot[t] / cnt;
        const float var  = tot[8 + t] / cnt - mean * mean;
        const float sc   = gamma[t] * rsqrtf(var + BN_EPS);
        scale_s[t] = sc;
        bp[t] = fmaf(bias[t] - mean, sc, beta[t]);   // (b - mean)*sc + beta
    }
    __syncthreads();
    if (t < 80) wp[t] = W[t] * scale_s[t / 10];
}

__global__ __launch_bounds__(256) void locse_out_kernel(
    const float* __restrict__ coords, const float* __restrict__ features,
    const int* __restrict__ idx, const float* __restrict__ dist,
    const float* __restrict__ wp, const float* __restrict__ bp,
    float* __restrict__ out)
{
    __shared__ float sA[24];
    __shared__ float sB[24];
    __shared__ float sw9[8];
    __shared__ float sbb[8];
    if (threadIdx.x < 24) {
        const int d = threadIdx.x / 3, j = threadIdx.x % 3;
        sA[threadIdx.x] = wp[d * 10 + j] + wp[d * 10 + 6 + j];
        sB[threadIdx.x] = wp[d * 10 + 3 + j] - wp[d * 10 + 6 + j];
    }
    if (threadIdx.x < 8) {
        sw9[threadIdx.x] = wp[threadIdx.x * 10 + 9];
        sbb[threadIdx.x] = bp[threadIdx.x];
    }
    __syncthreads();

    const int t = blockIdx.x * blockDim.x + threadIdx.x;   // grid == TOTAL4 exactly
    const int k4 = t & 3;
    const int bn = t >> 2;
    const int b  = bn / NN;
    const int n  = bn - b * NN;
    const float* cc = coords + (size_t)bn * 3;
    const float cx = cc[0], cy = cc[1], cz = cc[2];

    float cA[8];
    #pragma unroll
    for (int d = 0; d < 8; ++d)
        cA[d] = fmaf(sA[d * 3 + 2], cz,
                fmaf(sA[d * 3 + 1], cy,
                fmaf(sA[d * 3 + 0], cx, sbb[d])));

    const int base = (bn << 4) + (k4 << 2);
    const int4   j4 = *reinterpret_cast<const int4*>(idx + base);
    const float4 d4 = *reinterpret_cast<const float4*>(dist + base);
    const int   js[4] = {j4.x, j4.y, j4.z, j4.w};
    const float ds[4] = {d4.x, d4.y, d4.z, d4.w};

    float hv[8][4];
    #pragma unroll
    for (int kk = 0; kk < 4; ++kk) {
        const float* nc = coords + ((size_t)b * NN + js[kk]) * 3;
        const float nx = nc[0], ny = nc[1], nz = nc[2];
        #pragma unroll
        for (int d = 0; d < 8; ++d) {
            const float h = fmaf(sw9[d], ds[kk],
                            fmaf(sB[d * 3 + 2], nz,
                            fmaf(sB[d * 3 + 1], ny,
                            fmaf(sB[d * 3 + 0], nx, cA[d]))));
            hv[d][kk] = fmaxf(h, 0.f);
        }
    }

    // out[b, ch, n, k]: base offset for (b, ch=0, n, k4*4)
    const size_t outn = (size_t)b * 16 * NN * KK + (size_t)n * KK + (k4 << 2);
    #pragma unroll
    for (int d = 0; d < 8; ++d) {
        *reinterpret_cast<float4*>(out + outn + (size_t)d * NN * KK) =
            make_float4(hv[d][0], hv[d][1], hv[d][2], hv[d][3]);
    }
    #pragma unroll
    for (int d = 0; d < 8; ++d) {
        const float f = features[((size_t)b * DD + d) * NN + n];
        *reinterpret_cast<float4*>(out + outn + (size_t)(8 + d) * NN * KK) =
            make_float4(f, f, f, f);
    }
}

extern "C" void kernel_launch(void* const* d_in, const int* in_sizes, int n_in,
                              void* d_out, int out_size, void* d_ws, size_t ws_size,
                              hipStream_t stream) {
    const float* coords   = (const float*)d_in[0];
    const float* features = (const float*)d_in[1];
    const int*   idx      = (const int*)d_in[2];
    const float* dist     = (const float*)d_in[3];
    const float* W        = (const float*)d_in[4];
    const float* bias     = (const float*)d_in[5];
    const float* gamma    = (const float*)d_in[6];
    const float* beta     = (const float*)d_in[7];
    float* out = (float*)d_out;

    float* wsf      = (float*)d_ws;
    float* partials = wsf;
    float* wp       = wsf + STATS_BLOCKS * 16;
    float* bp       = wp + 80;

    locse_stats_kernel<<<dim3(STATS_BLOCKS), dim3(STATS_THREADS), 0, stream>>>(
        coords, idx, dist, W, bias, partials);
    locse_finalize_kernel<<<dim3(1), dim3(256), 0, stream>>>(
        partials, W, bias, gamma, beta, wp, bp);

    const int blocks = TOTAL4 / 256;   // 2560, exact
    locse_out_kernel<<<dim3(blocks), dim3(256), 0, stream>>>(
        coords, features, idx, dist, wp, bp, out);
}

// Round 6
// 248.986 us; speedup vs baseline: 1.0833x; 1.0549x over previous
//
#include <hip/hip_runtime.h>

// Problem constants (match reference setup_inputs)
constexpr int BB = 4;
constexpr int NN = 40960;
constexpr int KK = 16;
constexpr int DD = 8;
constexpr float BN_EPS = 1e-6f;

constexpr int PTS    = BB * NN;               // 163840 points
constexpr int TOTAL4 = BB * NN * (KK / 4);    // 655360 work items (4 k each)

constexpr int STATS_BLOCKS   = 512;
constexpr int STATS_THREADS  = 640;
constexpr int STATS_NTHREADS = STATS_BLOCKS * STATS_THREADS;  // 327680
constexpr int STATS_ITEMS    = TOTAL4 / STATS_NTHREADS;       // 2, exact
static_assert(STATS_ITEMS * STATS_NTHREADS == TOTAL4, "balanced grid");

typedef float f32x4 __attribute__((ext_vector_type(4)));

// ws layout (floats):
//   [0 .. 8192)            per-block partials (8 sums, 8 sumsqs) x 512 blocks
//   [8192 .. 8272)         W' (BN-folded conv weight, 8x10)
//   [8272 .. 8280)         b' (BN-folded bias, 8)
//   [8448 .. 8448+4*PTS)   float4-padded coords (16B-aligned gathers)
constexpr int    WS_WP     = STATS_BLOCKS * 16;   // 8192
constexpr int    WS_BP     = WS_WP + 80;          // 8272
constexpr int    WS_CP     = 8448;                // 33792 B offset, 16B aligned
constexpr size_t WS_NEEDED = (size_t)(WS_CP + 4 * PTS) * sizeof(float);

// h = W . [c, nb, c-nb, dist] + b  ==  (b + A.c) + B.nb + w9*dist
//   A[d][j] = W[d][j] + W[d][6+j],  B[d][j] = W[d][3+j] - W[d][6+j]
// (fold is linear, so it applies equally to the BN-scaled wp/bp)

__global__ __launch_bounds__(256) void pad_coords_kernel(
    const float* __restrict__ coords, float* __restrict__ cp)
{
    const int i = blockIdx.x * blockDim.x + threadIdx.x;   // one point each
    if (i < PTS) {
        const float* s = coords + (size_t)i * 3;
        const f32x4 v = {s[0], s[1], s[2], 0.f};
        *reinterpret_cast<f32x4*>(cp + (size_t)i * 4) = v;
    }
}

// Stats pass: conv + sum/sumsq accumulation AND the BN-independent
// feature-broadcast half of the output (overlaps store BW with the
// latency-bound gather phase).
template <bool PADDED>
__global__ __launch_bounds__(STATS_THREADS, 5) void locse_stats_kernel(
    const float* __restrict__ coords, const float* __restrict__ cp,
    const float* __restrict__ features, const int* __restrict__ idx,
    const float* __restrict__ dist, const float* __restrict__ W,
    const float* __restrict__ bias, float* __restrict__ partials,
    float* __restrict__ out)
{
    __shared__ float sA[24];   // [d][j]
    __shared__ float sB[24];
    __shared__ float sw9[8];
    __shared__ float sbb[8];
    if (threadIdx.x < 24) {
        const int d = threadIdx.x / 3, j = threadIdx.x % 3;
        sA[threadIdx.x] = W[d * 10 + j] + W[d * 10 + 6 + j];
        sB[threadIdx.x] = W[d * 10 + 3 + j] - W[d * 10 + 6 + j];
    }
    if (threadIdx.x < 8) {
        sw9[threadIdx.x] = W[threadIdx.x * 10 + 9];
        sbb[threadIdx.x] = bias[threadIdx.x];
    }
    __syncthreads();

    float sum[8] = {0.f, 0.f, 0.f, 0.f, 0.f, 0.f, 0.f, 0.f};
    float sq[8]  = {0.f, 0.f, 0.f, 0.f, 0.f, 0.f, 0.f, 0.f};

    const int tau = blockIdx.x * STATS_THREADS + threadIdx.x;
    #pragma unroll
    for (int it = 0; it < STATS_ITEMS; ++it) {
        const int t  = tau + it * STATS_NTHREADS;   // coalesced per wave
        const int k4 = t & 3;
        const int bn = t >> 2;               // b*NN + n
        const int b  = bn / NN;
        const int n  = bn - b * NN;

        float cx, cy, cz;
        if (PADDED) {
            const f32x4 c4 = *reinterpret_cast<const f32x4*>(cp + (size_t)bn * 4);
            cx = c4.x; cy = c4.y; cz = c4.z;
        } else {
            const float* cc = coords + (size_t)bn * 3;
            cx = cc[0]; cy = cc[1]; cz = cc[2];
        }

        float cA[8];
        #pragma unroll
        for (int d = 0; d < 8; ++d)
            cA[d] = fmaf(sA[d * 3 + 2], cz,
                    fmaf(sA[d * 3 + 1], cy,
                    fmaf(sA[d * 3 + 0], cx, sbb[d])));

        const int base = (bn << 4) + (k4 << 2);   // 16B aligned
        const int4   j4 = *reinterpret_cast<const int4*>(idx + base);
        const float4 d4 = *reinterpret_cast<const float4*>(dist + base);
        const int   js[4] = {j4.x, j4.y, j4.z, j4.w};
        const float ds[4] = {d4.x, d4.y, d4.z, d4.w};

        #pragma unroll
        for (int kk = 0; kk < 4; ++kk) {
            float nx, ny, nz;
            if (PADDED) {
                const f32x4 nb4 = *reinterpret_cast<const f32x4*>(
                    cp + ((size_t)b * NN + js[kk]) * 4);
                nx = nb4.x; ny = nb4.y; nz = nb4.z;
            } else {
                const float* nc = coords + ((size_t)b * NN + js[kk]) * 3;
                nx = nc[0]; ny = nc[1]; nz = nc[2];
            }
            #pragma unroll
            for (int d = 0; d < 8; ++d) {
                float h = fmaf(sw9[d], ds[kk],
                          fmaf(sB[d * 3 + 2], nz,
                          fmaf(sB[d * 3 + 1], ny,
                          fmaf(sB[d * 3 + 0], nx, cA[d]))));
                sum[d] += h;
                sq[d]  += h * h;
            }
        }

        // BN-independent feature-broadcast half of the output
        const size_t outn = (size_t)b * 16 * NN * KK + (size_t)n * KK + (k4 << 2);
        #pragma unroll
        for (int d = 0; d < 8; ++d) {
            const float f = features[((size_t)b * DD + d) * NN + n];
            *reinterpret_cast<float4*>(out + outn + (size_t)(8 + d) * NN * KK) =
                make_float4(f, f, f, f);
        }
    }

    // wave (64-lane) shuffle reduction for all 16 quantities
    #pragma unroll
    for (int v = 0; v < 8; ++v) {
        float s = sum[v], q = sq[v];
        #pragma unroll
        for (int off = 32; off > 0; off >>= 1) {
            s += __shfl_down(s, off, 64);
            q += __shfl_down(q, off, 64);
        }
        sum[v] = s; sq[v] = q;
    }

    __shared__ float wred[STATS_THREADS / 64][16];
    const int lane = threadIdx.x & 63;
    const int wid  = threadIdx.x >> 6;
    if (lane == 0) {
        #pragma unroll
        for (int v = 0; v < 8; ++v) {
            wred[wid][v]     = sum[v];
            wred[wid][8 + v] = sq[v];
        }
    }
    __syncthreads();
    if (threadIdx.x < 16) {
        float s = 0.f;
        #pragma unroll
        for (int w = 0; w < STATS_THREADS / 64; ++w) s += wred[w][threadIdx.x];
        partials[blockIdx.x * 16 + threadIdx.x] = s;
    }
}

__global__ __launch_bounds__(256) void locse_finalize_kernel(
    const float* __restrict__ partials, const float* __restrict__ W,
    const float* __restrict__ bias, const float* __restrict__ gamma,
    const float* __restrict__ beta, float* __restrict__ wp,
    float* __restrict__ bp)
{
    const int t = threadIdx.x;
    const int c = t & 15;
    float acc = 0.f;
    for (int i = t >> 4; i < STATS_BLOCKS; i += 16) acc += partials[i * 16 + c];

    __shared__ float red[256];
    __shared__ float tot[16];
    __shared__ float scale_s[8];
    red[t] = acc;
    __syncthreads();
    if (t < 16) {
        float s = 0.f;
        #pragma unroll
        for (int i = 0; i < 16; ++i) s += red[i * 16 + t];
        tot[t] = s;
    }
    __syncthreads();
    if (t < 8) {
        const float cnt  = (float)BB * (float)NN * (float)KK;
        const float mean = tot[t] / cnt;
        const float var  = tot[8 + t] / cnt - mean * mean;
        const float sc   = gamma[t] * rsqrtf(var + BN_EPS);
        scale_s[t] = sc;
        bp[t] = fmaf(bias[t] - mean, sc, beta[t]);   // (b - mean)*sc + beta
    }
    __syncthreads();
    if (t < 80) wp[t] = W[t] * scale_s[t / 10];
}

// Output pass: h channels only (feature channels already written by stats).
template <bool PADDED>
__global__ __launch_bounds__(256) void locse_out_kernel(
    const float* __restrict__ coords, const float* __restrict__ cp,
    const int* __restrict__ idx, const float* __restrict__ dist,
    const float* __restrict__ wp, const float* __restrict__ bp,
    float* __restrict__ out)
{
    __shared__ float sA[24];
    __shared__ float sB[24];
    __shared__ float sw9[8];
    __shared__ float sbb[8];
    if (threadIdx.x < 24) {
        const int d = threadIdx.x / 3, j = threadIdx.x % 3;
        sA[threadIdx.x] = wp[d * 10 + j] + wp[d * 10 + 6 + j];
        sB[threadIdx.x] = wp[d * 10 + 3 + j] - wp[d * 10 + 6 + j];
    }
    if (threadIdx.x < 8) {
        sw9[threadIdx.x] = wp[threadIdx.x * 10 + 9];
        sbb[threadIdx.x] = bp[threadIdx.x];
    }
    __syncthreads();

    const int t  = blockIdx.x * blockDim.x + threadIdx.x;  // grid == TOTAL4
    const int k4 = t & 3;
    const int bn = t >> 2;
    const int b  = bn / NN;
    const int n  = bn - b * NN;

    float cx, cy, cz;
    if (PADDED) {
        const f32x4 c4 = *reinterpret_cast<const f32x4*>(cp + (size_t)bn * 4);
        cx = c4.x; cy = c4.y; cz = c4.z;
    } else {
        const float* cc = coords + (size_t)bn * 3;
        cx = cc[0]; cy = cc[1]; cz = cc[2];
    }

    float cA[8];
    #pragma unroll
    for (int d = 0; d < 8; ++d)
        cA[d] = fmaf(sA[d * 3 + 2], cz,
                fmaf(sA[d * 3 + 1], cy,
                fmaf(sA[d * 3 + 0], cx, sbb[d])));

    const int base = (bn << 4) + (k4 << 2);
    const int4   j4 = *reinterpret_cast<const int4*>(idx + base);
    const float4 d4 = *reinterpret_cast<const float4*>(dist + base);
    const int   js[4] = {j4.x, j4.y, j4.z, j4.w};
    const float ds[4] = {d4.x, d4.y, d4.z, d4.w};

    float hv[8][4];
    #pragma unroll
    for (int kk = 0; kk < 4; ++kk) {
        float nx, ny, nz;
        if (PADDED) {
            const f32x4 nb4 = *reinterpret_cast<const f32x4*>(
                cp + ((size_t)b * NN + js[kk]) * 4);
            nx = nb4.x; ny = nb4.y; nz = nb4.z;
        } else {
            const float* nc = coords + ((size_t)b * NN + js[kk]) * 3;
            nx = nc[0]; ny = nc[1]; nz = nc[2];
        }
        #pragma unroll
        for (int d = 0; d < 8; ++d) {
            const float h = fmaf(sw9[d], ds[kk],
                            fmaf(sB[d * 3 + 2], nz,
                            fmaf(sB[d * 3 + 1], ny,
                            fmaf(sB[d * 3 + 0], nx, cA[d]))));
            hv[d][kk] = fmaxf(h, 0.f);
        }
    }

    const size_t outn = (size_t)b * 16 * NN * KK + (size_t)n * KK + (k4 << 2);
    #pragma unroll
    for (int d = 0; d < 8; ++d) {
        *reinterpret_cast<float4*>(out + outn + (size_t)d * NN * KK) =
            make_float4(hv[d][0], hv[d][1], hv[d][2], hv[d][3]);
    }
}

extern "C" void kernel_launch(void* const* d_in, const int* in_sizes, int n_in,
                              void* d_out, int out_size, void* d_ws, size_t ws_size,
                              hipStream_t stream) {
    const float* coords   = (const float*)d_in[0];
    const float* features = (const float*)d_in[1];
    const int*   idx      = (const int*)d_in[2];
    const float* dist     = (const float*)d_in[3];
    const float* W        = (const float*)d_in[4];
    const float* bias     = (const float*)d_in[5];
    const float* gamma    = (const float*)d_in[6];
    const float* beta     = (const float*)d_in[7];
    float* out = (float*)d_out;

    float* wsf      = (float*)d_ws;
    float* partials = wsf;
    float* wp       = wsf + WS_WP;
    float* bp       = wsf + WS_BP;
    float* cp       = wsf + WS_CP;

    const bool padded = ws_size >= WS_NEEDED;
    const int out_blocks = TOTAL4 / 256;   // 2560, exact

    if (padded) {
        pad_coords_kernel<<<dim3((PTS + 255) / 256), dim3(256), 0, stream>>>(
            coords, cp);
        locse_stats_kernel<true>
            <<<dim3(STATS_BLOCKS), dim3(STATS_THREADS), 0, stream>>>(
                coords, cp, features, idx, dist, W, bias, partials, out);
        locse_finalize_kernel<<<dim3(1), dim3(256), 0, stream>>>(
            partials, W, bias, gamma, beta, wp, bp);
        locse_out_kernel<true><<<dim3(out_blocks), dim3(256), 0, stream>>>(
            coords, cp, idx, dist, wp, bp, out);
    } else {
        locse_stats_kernel<false>
            <<<dim3(STATS_BLOCKS), dim3(STATS_THREADS), 0, stream>>>(
                coords, cp, features, idx, dist, W, bias, partials, out);
        locse_finalize_kernel<<<dim3(1), dim3(256), 0, stream>>>(
            partials, W, bias, gamma, beta, wp, bp);
        locse_out_kernel<false><<<dim3(out_blocks), dim3(256), 0, stream>>>(
            coords, cp, idx, dist, wp, bp, out);
    }
}